// Round 1
// baseline (80992.365 us; speedup 1.0000x reference)
//
#include <hip/hip_runtime.h>
#include <hip/hip_cooperative_groups.h>

namespace cg = cooperative_groups;

#define TT 512
#define BB 64
#define IDIM 256
#define CDIM 512
#define NMEM 128
#define MDIM 64
#define KTOT 832     // (IDIM + M) + CDIM = 320 + 512
#define ODIM 576     // CDIM + M
#define NROWS 2048   // 4*CDIM

struct Params {
  const float* embs; const float* W_ih; const float* W_hh; const float* b_ih; const float* b_hh;
  const float* W_kr; const float* b_kr; const float* w_br; const float* W_kw; const float* b_kw;
  const float* w_bw; const float* W_e; const float* b_e; const float* W_a; const float* b_a;
  const float* h0; const float* c0; const float* r0; const float* mem0;
  float* out;
  float* Wopt;   // [2048*832] reordered as [w][k][lr]
  float* h_buf;  // [2][B*CDIM] double buffered
  float* r_buf;  // [B*M]
};

__device__ __forceinline__ float sigmoidf_(float x) { return 1.0f / (1.0f + __expf(-x)); }
__device__ __forceinline__ float tanhf_(float x) {
  float e = __expf(-2.0f * fabsf(x));
  float t = (1.0f - e) / (1.0f + e);
  return copysignf(t, x);
}
__device__ __forceinline__ float softplusf_(float x) {
  return (x > 20.0f) ? x : log1pf(__expf(x));
}
__device__ __forceinline__ float wred_sum(float v) {
#pragma unroll
  for (int off = 32; off > 0; off >>= 1) v += __shfl_xor(v, off, 64);
  return v;
}
__device__ __forceinline__ float wred_max(float v) {
#pragma unroll
  for (int off = 32; off > 0; off >>= 1) v = fmaxf(v, __shfl_xor(v, off, 64));
  return v;
}

// Pre-transpose combined weights into Wopt[(w*832 + k)*8 + lr],
// lr -> global gate row = 512*(lr>>1) + 2*w + (lr&1)
__global__ void __launch_bounds__(256) transpose_w_kernel(const float* __restrict__ W_ih,
                                                          const float* __restrict__ W_hh,
                                                          float* __restrict__ Wopt) {
  int idx = blockIdx.x * 256 + threadIdx.x;
  if (idx >= NROWS * KTOT) return;
  int lr = idx & 7;
  int rem = idx >> 3;          // w*832 + k
  int k = rem % KTOT;
  int w = rem / KTOT;
  int row = 512 * (lr >> 1) + 2 * w + (lr & 1);
  float v = (k < 320) ? W_ih[(size_t)row * 320 + k] : W_hh[(size_t)row * 512 + (k - 320)];
  Wopt[idx] = v;
}

__global__ void __launch_bounds__(256) mann_kernel(Params p) {
  const int w = blockIdx.x;       // 0..255 : owns c-dims {2w, 2w+1}
  const int tid = threadIdx.x;
  const int lane = tid & 63;
  const int q = tid >> 6;         // wave id 0..3

  // phase-A staging (xs aliased with cross-wave reduce buffer)
  __shared__ __align__(16) float xs[64 * 65];          // [kk][b] stride 65 (conflict-free)
  __shared__ __align__(16) float ws[64][8];            // [kk][lr]
  __shared__ float bsum[8];
  // phase-B (batch WGs only)
  __shared__ __align__(16) float Mem_s[MDIM][NMEM + 1];  // [m][n] stride 129 (conflict-free)
  __shared__ __align__(16) float hb[CDIM];
  __shared__ float kw_s[MDIM], kr_s[MDIM], e_s[MDIM], a_s[MDIM];
  __shared__ float ww_s[NMEM], wr_s[NMEM];
  __shared__ float sc[8];  // 0:betaw 1:betar 2:|kw| 3:|kr| 4,5:max parts 6,7:sum parts

  cg::grid_group grid = cg::this_grid();

  // ---------------- init ----------------
  if (tid < 8) {
    int row = 512 * (tid >> 1) + 2 * w + (tid & 1);
    bsum[tid] = p.b_ih[row] + p.b_hh[row];
  }
  float c_reg = 0.0f;  // valid for tid<128: cell state for (b=tid&63, j=2w+(tid>>6))
  if (tid < 128) {
    int jj = tid >> 6, b = tid & 63;
    int j = 2 * w + jj;
    c_reg = p.c0[j];
    p.h_buf[(size_t)b * CDIM + j] = p.h0[j];  // h_buf[0]
  }
  if (w < BB) {
    for (int idx = tid; idx < NMEM * MDIM; idx += 256) {
      int n = idx >> 6, m = idx & 63;
      Mem_s[m][n] = p.mem0[idx];  // mem0[n][m] -> Mem_s[m][n]
    }
    if (tid < MDIM) p.r_buf[w * MDIM + tid] = p.r0[tid];
  }
  __threadfence();
  grid.sync();

#pragma unroll 1
  for (int t = 0; t < TT; ++t) {
    const float* h_read = p.h_buf + (size_t)(t & 1) * (BB * CDIM);
    float* h_write = p.h_buf + (size_t)((t + 1) & 1) * (BB * CDIM);

    // ---------------- Phase A: gates GEMM + LSTM ----------------
    float acc[8];
#pragma unroll
    for (int i = 0; i < 8; ++i) acc[i] = 0.0f;

#pragma unroll 1
    for (int c = 0; c < 13; ++c) {
      // stage x chunk: x[b][64c + kk], all 256 threads cooperate
      {
        const int k0 = c * 64;
        const int kk4 = (tid & 15) * 4;
        const int bb0 = tid >> 4;
#pragma unroll
        for (int i = 0; i < 4; ++i) {
          const int b = bb0 + 16 * i;
          const int k = k0 + kk4;
          float4 v;
          if (c < 4)       v = *(const float4*)(p.embs + ((size_t)t * BB + b) * IDIM + k);
          else if (c == 4) v = *(const float4*)(p.r_buf + b * MDIM + (k - 256));
          else             v = *(const float4*)(h_read + (size_t)b * CDIM + (k - 320));
          xs[(kk4 + 0) * 65 + b] = v.x;
          xs[(kk4 + 1) * 65 + b] = v.y;
          xs[(kk4 + 2) * 65 + b] = v.z;
          xs[(kk4 + 3) * 65 + b] = v.w;
        }
      }
      // stage weight chunk (coalesced from Wopt)
      {
        const float* src = p.Wopt + ((size_t)w * KTOT + c * 64) * 8;
        ((float*)ws)[tid] = src[tid];
        ((float*)ws)[tid + 256] = src[tid + 256];
      }
      __syncthreads();
      // wave q computes kk in [16q, 16q+16) for all 8 rows (K-split across waves)
      const int kkb = 16 * q;
#pragma unroll
      for (int kki = 0; kki < 16; ++kki) {
        const int kk = kkb + kki;
        const float xv = xs[kk * 65 + lane];
        const float4 w0 = *(const float4*)&ws[kk][0];
        const float4 w1 = *(const float4*)&ws[kk][4];
        acc[0] = fmaf(xv, w0.x, acc[0]);
        acc[1] = fmaf(xv, w0.y, acc[1]);
        acc[2] = fmaf(xv, w0.z, acc[2]);
        acc[3] = fmaf(xv, w0.w, acc[3]);
        acc[4] = fmaf(xv, w1.x, acc[4]);
        acc[5] = fmaf(xv, w1.y, acc[5]);
        acc[6] = fmaf(xv, w1.z, acc[6]);
        acc[7] = fmaf(xv, w1.w, acc[7]);
      }
      __syncthreads();
    }
    // cross-wave K reduction (reuse xs region)
    {
      float* red = xs;  // [q][lr][b] = [4][8][64]
#pragma unroll
      for (int lr = 0; lr < 8; ++lr) red[(q * 8 + lr) * 64 + lane] = acc[lr];
      __syncthreads();
      if (tid < 128) {
        const int jj = tid >> 6, b = tid & 63;
        float g[4];
#pragma unroll
        for (int gate = 0; gate < 4; ++gate) {
          const int lr = gate * 2 + jj;
          float s = bsum[lr];
#pragma unroll
          for (int qq = 0; qq < 4; ++qq) s += red[(qq * 8 + lr) * 64 + b];
          g[gate] = s;
        }
        const float iv = sigmoidf_(g[0]);
        const float fv = sigmoidf_(g[1]);
        const float gv = tanhf_(g[2]);
        const float ov = sigmoidf_(g[3]);
        c_reg = fv * c_reg + iv * gv;
        const float hv = ov * tanhf_(c_reg);
        h_write[(size_t)b * CDIM + 2 * w + jj] = hv;
      }
    }
    __threadfence();
    grid.sync();

    // ---------------- Phase B: heads + addressing + memory (batch WGs) ----------------
    if (w < BB) {
      const int b = w;
      hb[tid] = h_write[(size_t)b * CDIM + tid];
      hb[tid + 256] = h_write[(size_t)b * CDIM + tid + 256];
      __syncthreads();
      // head GEMVs: [0,64):kw  [64,128):e  [128,192):kr  192:betaw 193:betar
      if (tid < 194) {
        const float* Wrow;
        if (tid < 64)        Wrow = p.W_kw + (size_t)tid * CDIM;
        else if (tid < 128)  Wrow = p.W_e + (size_t)(tid - 64) * CDIM;
        else if (tid < 192)  Wrow = p.W_kr + (size_t)(tid - 128) * CDIM;
        else if (tid == 192) Wrow = p.w_bw;
        else                 Wrow = p.w_br;
        float s = 0.0f;
#pragma unroll 4
        for (int k = 0; k < CDIM; k += 4) {
          const float4 wv = *(const float4*)(Wrow + k);
          s = fmaf(wv.x, hb[k], s);
          s = fmaf(wv.y, hb[k + 1], s);
          s = fmaf(wv.z, hb[k + 2], s);
          s = fmaf(wv.w, hb[k + 3], s);
        }
        if (tid < 64)       kw_s[tid] = tanhf_(s + p.b_kw[tid]);
        else if (tid < 128) e_s[tid - 64] = sigmoidf_(s + p.b_e[tid - 64]);
        else if (tid < 192) kr_s[tid - 128] = tanhf_(s + p.b_kr[tid - 128]);
        else                sc[tid - 192] = softplusf_(s);
      }
      // a = tanh(emb @ W_a^T + b_a)
      if (tid < 64) {
        const float* Wrow = p.W_a + (size_t)tid * IDIM;
        const float* eb = p.embs + ((size_t)t * BB + b) * IDIM;
        float s = p.b_a[tid];
#pragma unroll 4
        for (int k = 0; k < IDIM; k += 4) {
          const float4 wv = *(const float4*)(Wrow + k);
          const float4 ev = *(const float4*)(eb + k);
          s = fmaf(wv.x, ev.x, s);
          s = fmaf(wv.y, ev.y, s);
          s = fmaf(wv.z, ev.z, s);
          s = fmaf(wv.w, ev.w, s);
        }
        a_s[tid] = tanhf_(s);
      }
      __syncthreads();
      // key norms: wave0 -> |kw|, wave1 -> |kr|
      if (tid < 128) {
        const float v = (q == 0) ? kw_s[lane] : kr_s[lane];
        const float ss = wred_sum(v * v);
        if (lane == 0) sc[2 + q] = sqrtf(ss);
      }
      __syncthreads();
      // ---- write addressing (on old Mem) ----
      {
        float logit = 0.0f, ex = 0.0f;
        const float beta = sc[0], keyn = sc[2];
        if (tid < 128) {
          float sim = 0.0f, nrm = 0.0f;
#pragma unroll 8
          for (int m = 0; m < MDIM; ++m) {
            const float mv = Mem_s[m][tid];
            sim = fmaf(mv, kw_s[m], sim);
            nrm = fmaf(mv, mv, nrm);
          }
          logit = beta * sim / (sqrtf(nrm) * keyn + 1e-8f);
          const float mx = wred_max(logit);
          if (lane == 0) sc[4 + q] = mx;
        }
        __syncthreads();
        if (tid < 128) {
          ex = __expf(logit - fmaxf(sc[4], sc[5]));
          const float sm = wred_sum(ex);
          if (lane == 0) sc[6 + q] = sm;
        }
        __syncthreads();
        if (tid < 128) ww_s[tid] = ex / (sc[6] + sc[7]);
        __syncthreads();
      }
      // ---- memory write (erase/add) ----
      for (int idx = tid; idx < NMEM * MDIM; idx += 256) {
        const int m = idx >> 7, n = idx & 127;
        const float mv = Mem_s[m][n];
        Mem_s[m][n] = mv * (1.0f - ww_s[n] * e_s[m]) + ww_s[n] * a_s[m];
      }
      __syncthreads();
      // ---- read addressing (on new Mem) ----
      {
        float logit = 0.0f, ex = 0.0f;
        const float beta = sc[1], keyn = sc[3];
        if (tid < 128) {
          float sim = 0.0f, nrm = 0.0f;
#pragma unroll 8
          for (int m = 0; m < MDIM; ++m) {
            const float mv = Mem_s[m][tid];
            sim = fmaf(mv, kr_s[m], sim);
            nrm = fmaf(mv, mv, nrm);
          }
          logit = beta * sim / (sqrtf(nrm) * keyn + 1e-8f);
          const float mx = wred_max(logit);
          if (lane == 0) sc[4 + q] = mx;
        }
        __syncthreads();
        if (tid < 128) {
          ex = __expf(logit - fmaxf(sc[4], sc[5]));
          const float sm = wred_sum(ex);
          if (lane == 0) sc[6 + q] = sm;
        }
        __syncthreads();
        if (tid < 128) wr_s[tid] = ex / (sc[6] + sc[7]);
        __syncthreads();
      }
      // ---- read vector + outputs ----
      if (tid < 64) {
        float rv = 0.0f;
#pragma unroll 8
        for (int n = 0; n < NMEM; ++n) rv = fmaf(wr_s[n], Mem_s[tid][n], rv);
        p.r_buf[b * MDIM + tid] = rv;
        p.out[((size_t)t * BB + b) * ODIM + 512 + tid] = rv;
      }
      p.out[((size_t)t * BB + b) * ODIM + tid] = hb[tid];
      p.out[((size_t)t * BB + b) * ODIM + 256 + tid] = hb[tid + 256];
    }
    __threadfence();
    grid.sync();
  }
}

extern "C" void kernel_launch(void* const* d_in, const int* in_sizes, int n_in,
                              void* d_out, int out_size, void* d_ws, size_t ws_size,
                              hipStream_t stream) {
  (void)in_sizes; (void)n_in; (void)out_size; (void)ws_size;
  Params p;
  p.embs = (const float*)d_in[0];
  p.W_ih = (const float*)d_in[1];
  p.W_hh = (const float*)d_in[2];
  p.b_ih = (const float*)d_in[3];
  p.b_hh = (const float*)d_in[4];
  p.W_kr = (const float*)d_in[5];
  p.b_kr = (const float*)d_in[6];
  p.w_br = (const float*)d_in[7];
  p.W_kw = (const float*)d_in[8];
  p.b_kw = (const float*)d_in[9];
  p.w_bw = (const float*)d_in[10];
  p.W_e  = (const float*)d_in[11];
  p.b_e  = (const float*)d_in[12];
  p.W_a  = (const float*)d_in[13];
  p.b_a  = (const float*)d_in[14];
  p.h0   = (const float*)d_in[15];
  p.c0   = (const float*)d_in[16];
  p.r0   = (const float*)d_in[17];
  p.mem0 = (const float*)d_in[18];
  p.out = (float*)d_out;

  float* ws = (float*)d_ws;
  p.Wopt = ws;                              // 2048*832      = 1,703,936 floats
  p.h_buf = ws + (size_t)NROWS * KTOT;      // 2*64*512      = 65,536 floats
  p.r_buf = p.h_buf + 2 * BB * CDIM;        // 64*64         = 4,096 floats

  const int total = NROWS * KTOT;
  hipLaunchKernelGGL(transpose_w_kernel, dim3((total + 255) / 256), dim3(256), 0, stream,
                     p.W_ih, p.W_hh, p.Wopt);

  void* kargs[] = { (void*)&p };
  hipLaunchCooperativeKernel((const void*)mann_kernel, dim3(256), dim3(256), kargs, 0, stream);
}

// Round 2
// 34740.347 us; speedup vs baseline: 2.3314x; 2.3314x over previous
//
#include <hip/hip_runtime.h>

#define TT 512
#define BB 64
#define IDIM 256
#define CDIM 512
#define NMEM 128
#define MDIM 64
#define KTOT 832     // (IDIM + M) + CDIM = 320 + 512
#define ODIM 576     // CDIM + M
#define NROWS 2048   // 4*CDIM

struct Params {
  const float* embs; const float* W_ih; const float* W_hh; const float* b_ih; const float* b_hh;
  const float* W_kr; const float* b_kr; const float* w_br; const float* W_kw; const float* b_kw;
  const float* w_bw; const float* W_e; const float* b_e; const float* W_a; const float* b_a;
  const float* h0; const float* c0; const float* r0; const float* mem0;
  float* out;
  unsigned* bar;  // [96]: cnt0 @0, cnt1 @32, cnt2 @64 (128B-separated)
  float* Wopt;   // [2048*832] reordered as [w][k][lr]
  float* h_buf;  // [2][B*CDIM] double buffered
  float* r_buf;  // [B*M]
};

__device__ __forceinline__ float sigmoidf_(float x) { return 1.0f / (1.0f + __expf(-x)); }
__device__ __forceinline__ float tanhf_(float x) {
  float e = __expf(-2.0f * fabsf(x));
  float t = (1.0f - e) / (1.0f + e);
  return copysignf(t, x);
}
__device__ __forceinline__ float softplusf_(float x) {
  return (x > 20.0f) ? x : log1pf(__expf(x));
}
__device__ __forceinline__ float wred_sum(float v) {
#pragma unroll
  for (int off = 32; off > 0; off >>= 1) v += __shfl_xor(v, off, 64);
  return v;
}
__device__ __forceinline__ float wred_max(float v) {
#pragma unroll
  for (int off = 32; off > 0; off >>= 1) v = fmaxf(v, __shfl_xor(v, off, 64));
  return v;
}

// Cheap grid barrier primitives: one fence + one RMW per WG, not per thread.
__device__ __forceinline__ void bar_arrive(unsigned* c) {
  // caller: after __syncthreads(), tid==0 only
  __threadfence();  // release: flush WG's stores to the coherent point (1 wbl2/WG)
  __hip_atomic_fetch_add(c, 1u, __ATOMIC_RELAXED, __HIP_MEMORY_SCOPE_AGENT);
}
__device__ __forceinline__ void bar_wait(unsigned* c, unsigned target) {
  // tid==0 only; followed by __syncthreads() in caller
  while (__hip_atomic_load(c, __ATOMIC_RELAXED, __HIP_MEMORY_SCOPE_AGENT) < target)
    __builtin_amdgcn_s_sleep(2);
  __threadfence();  // acquire: invalidate stale L1/L2 lines (1 inv/WG)
}

// Pre-transpose combined weights into Wopt[(w*832 + k)*8 + lr],
// lr -> global gate row = 512*(lr>>1) + 2*w + (lr&1)
__global__ void __launch_bounds__(256) transpose_w_kernel(const float* __restrict__ W_ih,
                                                          const float* __restrict__ W_hh,
                                                          float* __restrict__ Wopt) {
  int idx = blockIdx.x * 256 + threadIdx.x;
  if (idx >= NROWS * KTOT) return;
  int lr = idx & 7;
  int rem = idx >> 3;          // w*832 + k
  int k = rem % KTOT;
  int w = rem / KTOT;
  int row = 512 * (lr >> 1) + 2 * w + (lr & 1);
  float v = (k < 320) ? W_ih[(size_t)row * 320 + k] : W_hh[(size_t)row * 512 + (k - 320)];
  Wopt[idx] = v;
}

__global__ void __launch_bounds__(256) mann_kernel(Params p) {
  const int w = blockIdx.x;       // 0..255 : owns c-dims {2w, 2w+1}
  const int tid = threadIdx.x;
  const int lane = tid & 63;
  const int q = tid >> 6;         // wave id 0..3

  // phase-A staging (xs aliased with cross-wave reduce buffer)
  __shared__ __align__(16) float xs[64 * 65];          // [kk][b] stride 65 (conflict-free)
  __shared__ __align__(16) float ws[64][8];            // [kk][lr]
  __shared__ float bsum[8];
  // phase-B (batch WGs only)
  __shared__ __align__(16) float Mem_s[MDIM][NMEM + 1];  // [m][n] stride 129 (conflict-free)
  __shared__ __align__(16) float hb[CDIM];
  __shared__ float kw_s[MDIM], kr_s[MDIM], e_s[MDIM], a_s[MDIM];
  __shared__ float ww_s[NMEM], wr_s[NMEM];
  __shared__ float sc[8];  // 0:betaw 1:betar 2:|kw| 3:|kr| 4,5:max parts 6,7:sum parts

  // ---------------- init ----------------
  if (tid < 8) {
    int row = 512 * (tid >> 1) + 2 * w + (tid & 1);
    bsum[tid] = p.b_ih[row] + p.b_hh[row];
  }
  float c_reg = 0.0f;  // valid for tid<128: cell state for (b=tid&63, j=2w+(tid>>6))
  if (tid < 128) {
    int jj = tid >> 6, b = tid & 63;
    int j = 2 * w + jj;
    c_reg = p.c0[j];
    p.h_buf[(size_t)b * CDIM + j] = p.h0[j];  // h_buf[0]
  }
  if (w < BB) {
    for (int idx = tid; idx < NMEM * MDIM; idx += 256) {
      int n = idx >> 6, m = idx & 63;
      Mem_s[m][n] = p.mem0[idx];  // mem0[n][m] -> Mem_s[m][n]
    }
    if (tid < MDIM) p.r_buf[w * MDIM + tid] = p.r0[tid];
  }
  __syncthreads();
  if (tid == 0) { bar_arrive(&p.bar[0]); bar_wait(&p.bar[0], 256u); }
  __syncthreads();

#pragma unroll 1
  for (int t = 0; t < TT; ++t) {
    const float* h_read = p.h_buf + (size_t)(t & 1) * (BB * CDIM);
    float* h_write = p.h_buf + (size_t)((t + 1) & 1) * (BB * CDIM);

    // ---------------- Phase A: gates GEMM + LSTM ----------------
    float acc[8];
#pragma unroll
    for (int i = 0; i < 8; ++i) acc[i] = 0.0f;

    const int kk4 = (tid & 15) * 4;
    const int bb0 = tid >> 4;

    // prefetch chunk 0 (x-slice + weight-slice) into registers
    float4 vbuf[4];
    float wsv0, wsv1;
    {
      const int k = kk4;  // chunk 0 -> embs
#pragma unroll
      for (int i = 0; i < 4; ++i) {
        const int b = bb0 + 16 * i;
        vbuf[i] = *(const float4*)(p.embs + ((size_t)t * BB + b) * IDIM + k);
      }
      const float* src = p.Wopt + (size_t)w * KTOT * 8;
      wsv0 = src[tid];
      wsv1 = src[tid + 256];
    }

#pragma unroll 1
    for (int c = 0; c < 13; ++c) {
      // store prefetched x chunk + weight chunk to LDS
#pragma unroll
      for (int i = 0; i < 4; ++i) {
        const int b = bb0 + 16 * i;
        xs[(kk4 + 0) * 65 + b] = vbuf[i].x;
        xs[(kk4 + 1) * 65 + b] = vbuf[i].y;
        xs[(kk4 + 2) * 65 + b] = vbuf[i].z;
        xs[(kk4 + 3) * 65 + b] = vbuf[i].w;
      }
      ((float*)ws)[tid] = wsv0;
      ((float*)ws)[tid + 256] = wsv1;
      __syncthreads();

      // issue next chunk's global loads (overlap with compute below)
      if (c < 12) {
        const int cn = c + 1;
        const int k = cn * 64 + kk4;
#pragma unroll
        for (int i = 0; i < 4; ++i) {
          const int b = bb0 + 16 * i;
          if (cn < 4)       vbuf[i] = *(const float4*)(p.embs + ((size_t)t * BB + b) * IDIM + k);
          else if (cn == 4) vbuf[i] = *(const float4*)(p.r_buf + b * MDIM + (k - 256));
          else              vbuf[i] = *(const float4*)(h_read + (size_t)b * CDIM + (k - 320));
        }
        const float* src = p.Wopt + ((size_t)w * KTOT + cn * 64) * 8;
        wsv0 = src[tid];
        wsv1 = src[tid + 256];
      }

      // wave q computes kk in [16q, 16q+16) for all 8 rows (K-split across waves)
      const int kkb = 16 * q;
#pragma unroll
      for (int kki = 0; kki < 16; ++kki) {
        const int kk = kkb + kki;
        const float xv = xs[kk * 65 + lane];
        const float4 w0 = *(const float4*)&ws[kk][0];
        const float4 w1 = *(const float4*)&ws[kk][4];
        acc[0] = fmaf(xv, w0.x, acc[0]);
        acc[1] = fmaf(xv, w0.y, acc[1]);
        acc[2] = fmaf(xv, w0.z, acc[2]);
        acc[3] = fmaf(xv, w0.w, acc[3]);
        acc[4] = fmaf(xv, w1.x, acc[4]);
        acc[5] = fmaf(xv, w1.y, acc[5]);
        acc[6] = fmaf(xv, w1.z, acc[6]);
        acc[7] = fmaf(xv, w1.w, acc[7]);
      }
      __syncthreads();
    }
    // cross-wave K reduction (reuse xs region)
    {
      float* red = xs;  // [q][lr][b] = [4][8][64]
#pragma unroll
      for (int lr = 0; lr < 8; ++lr) red[(q * 8 + lr) * 64 + lane] = acc[lr];
      __syncthreads();
      if (tid < 128) {
        const int jj = tid >> 6, b = tid & 63;
        float g[4];
#pragma unroll
        for (int gate = 0; gate < 4; ++gate) {
          const int lr = gate * 2 + jj;
          float s = bsum[lr];
#pragma unroll
          for (int qq = 0; qq < 4; ++qq) s += red[(qq * 8 + lr) * 64 + b];
          g[gate] = s;
        }
        const float iv = sigmoidf_(g[0]);
        const float fv = sigmoidf_(g[1]);
        const float gv = tanhf_(g[2]);
        const float ov = sigmoidf_(g[3]);
        c_reg = fv * c_reg + iv * gv;
        const float hv = ov * tanhf_(c_reg);
        h_write[(size_t)b * CDIM + 2 * w + jj] = hv;
      }
    }
    // ---- barrier 1: h complete. all arrive, all wait ----
    __syncthreads();
    if (tid == 0) { bar_arrive(&p.bar[32]); bar_wait(&p.bar[32], 256u * (t + 1)); }
    __syncthreads();

    // ---------------- Phase B: heads + addressing + memory (batch WGs) ----------------
    if (w < BB) {
      const int b = w;
      hb[tid] = h_write[(size_t)b * CDIM + tid];
      hb[tid + 256] = h_write[(size_t)b * CDIM + tid + 256];
      __syncthreads();
      // head GEMVs: [0,64):kw  [64,128):e  [128,192):kr  192:betaw 193:betar
      if (tid < 194) {
        const float* Wrow;
        if (tid < 64)        Wrow = p.W_kw + (size_t)tid * CDIM;
        else if (tid < 128)  Wrow = p.W_e + (size_t)(tid - 64) * CDIM;
        else if (tid < 192)  Wrow = p.W_kr + (size_t)(tid - 128) * CDIM;
        else if (tid == 192) Wrow = p.w_bw;
        else                 Wrow = p.w_br;
        float s = 0.0f;
#pragma unroll 4
        for (int k = 0; k < CDIM; k += 4) {
          const float4 wv = *(const float4*)(Wrow + k);
          s = fmaf(wv.x, hb[k], s);
          s = fmaf(wv.y, hb[k + 1], s);
          s = fmaf(wv.z, hb[k + 2], s);
          s = fmaf(wv.w, hb[k + 3], s);
        }
        if (tid < 64)       kw_s[tid] = tanhf_(s + p.b_kw[tid]);
        else if (tid < 128) e_s[tid - 64] = sigmoidf_(s + p.b_e[tid - 64]);
        else if (tid < 192) kr_s[tid - 128] = tanhf_(s + p.b_kr[tid - 128]);
        else                sc[tid - 192] = softplusf_(s);
      }
      // a = tanh(emb @ W_a^T + b_a)
      if (tid < 64) {
        const float* Wrow = p.W_a + (size_t)tid * IDIM;
        const float* eb = p.embs + ((size_t)t * BB + b) * IDIM;
        float s = p.b_a[tid];
#pragma unroll 4
        for (int k = 0; k < IDIM; k += 4) {
          const float4 wv = *(const float4*)(Wrow + k);
          const float4 ev = *(const float4*)(eb + k);
          s = fmaf(wv.x, ev.x, s);
          s = fmaf(wv.y, ev.y, s);
          s = fmaf(wv.z, ev.z, s);
          s = fmaf(wv.w, ev.w, s);
        }
        a_s[tid] = tanhf_(s);
      }
      __syncthreads();
      // key norms: wave0 -> |kw|, wave1 -> |kr|
      if (tid < 128) {
        const float v = (q == 0) ? kw_s[lane] : kr_s[lane];
        const float ss = wred_sum(v * v);
        if (lane == 0) sc[2 + q] = sqrtf(ss);
      }
      __syncthreads();
      // ---- write addressing (on old Mem) ----
      {
        float logit = 0.0f, ex = 0.0f;
        const float beta = sc[0], keyn = sc[2];
        if (tid < 128) {
          float sim = 0.0f, nrm = 0.0f;
#pragma unroll 8
          for (int m = 0; m < MDIM; ++m) {
            const float mv = Mem_s[m][tid];
            sim = fmaf(mv, kw_s[m], sim);
            nrm = fmaf(mv, mv, nrm);
          }
          logit = beta * sim / (sqrtf(nrm) * keyn + 1e-8f);
          const float mx = wred_max(logit);
          if (lane == 0) sc[4 + q] = mx;
        }
        __syncthreads();
        if (tid < 128) {
          ex = __expf(logit - fmaxf(sc[4], sc[5]));
          const float sm = wred_sum(ex);
          if (lane == 0) sc[6 + q] = sm;
        }
        __syncthreads();
        if (tid < 128) ww_s[tid] = ex / (sc[6] + sc[7]);
        __syncthreads();
      }
      // ---- memory write (erase/add) ----
      for (int idx = tid; idx < NMEM * MDIM; idx += 256) {
        const int m = idx >> 7, n = idx & 127;
        const float mv = Mem_s[m][n];
        Mem_s[m][n] = mv * (1.0f - ww_s[n] * e_s[m]) + ww_s[n] * a_s[m];
      }
      __syncthreads();
      // ---- read addressing (on new Mem) ----
      {
        float logit = 0.0f, ex = 0.0f;
        const float beta = sc[1], keyn = sc[3];
        if (tid < 128) {
          float sim = 0.0f, nrm = 0.0f;
#pragma unroll 8
          for (int m = 0; m < MDIM; ++m) {
            const float mv = Mem_s[m][tid];
            sim = fmaf(mv, kr_s[m], sim);
            nrm = fmaf(mv, mv, nrm);
          }
          logit = beta * sim / (sqrtf(nrm) * keyn + 1e-8f);
          const float mx = wred_max(logit);
          if (lane == 0) sc[4 + q] = mx;
        }
        __syncthreads();
        if (tid < 128) {
          ex = __expf(logit - fmaxf(sc[4], sc[5]));
          const float sm = wred_sum(ex);
          if (lane == 0) sc[6 + q] = sm;
        }
        __syncthreads();
        if (tid < 128) wr_s[tid] = ex / (sc[6] + sc[7]);
        __syncthreads();
      }
      // ---- read vector + outputs ----
      if (tid < 64) {
        float rv = 0.0f;
#pragma unroll 8
        for (int n = 0; n < NMEM; ++n) rv = fmaf(wr_s[n], Mem_s[tid][n], rv);
        p.r_buf[b * MDIM + tid] = rv;
        p.out[((size_t)t * BB + b) * ODIM + 512 + tid] = rv;
      }
      p.out[((size_t)t * BB + b) * ODIM + tid] = hb[tid];
      p.out[((size_t)t * BB + b) * ODIM + 256 + tid] = hb[tid + 256];
      // ---- barrier 2 arrive (r complete): only batch WGs arrive ----
      __syncthreads();
      if (tid == 0) bar_arrive(&p.bar[64]);
    }
    // ---- barrier 2 wait: everyone waits for the 64 batch WGs ----
    if (tid == 0) bar_wait(&p.bar[64], 64u * (t + 1));
    __syncthreads();
  }
}

extern "C" void kernel_launch(void* const* d_in, const int* in_sizes, int n_in,
                              void* d_out, int out_size, void* d_ws, size_t ws_size,
                              hipStream_t stream) {
  (void)in_sizes; (void)n_in; (void)out_size; (void)ws_size;
  Params p;
  p.embs = (const float*)d_in[0];
  p.W_ih = (const float*)d_in[1];
  p.W_hh = (const float*)d_in[2];
  p.b_ih = (const float*)d_in[3];
  p.b_hh = (const float*)d_in[4];
  p.W_kr = (const float*)d_in[5];
  p.b_kr = (const float*)d_in[6];
  p.w_br = (const float*)d_in[7];
  p.W_kw = (const float*)d_in[8];
  p.b_kw = (const float*)d_in[9];
  p.w_bw = (const float*)d_in[10];
  p.W_e  = (const float*)d_in[11];
  p.b_e  = (const float*)d_in[12];
  p.W_a  = (const float*)d_in[13];
  p.b_a  = (const float*)d_in[14];
  p.h0   = (const float*)d_in[15];
  p.c0   = (const float*)d_in[16];
  p.r0   = (const float*)d_in[17];
  p.mem0 = (const float*)d_in[18];
  p.out = (float*)d_out;

  float* ws = (float*)d_ws;
  p.bar = (unsigned*)ws;                    // 96 uints (384 B), zeroed below
  p.Wopt = ws + 96;                         // 2048*832      = 1,703,936 floats
  p.h_buf = p.Wopt + (size_t)NROWS * KTOT;  // 2*64*512      = 65,536 floats
  p.r_buf = p.h_buf + 2 * BB * CDIM;        // 64*64         = 4,096 floats

  hipMemsetAsync(p.bar, 0, 96 * sizeof(unsigned), stream);

  const int total = NROWS * KTOT;
  hipLaunchKernelGGL(transpose_w_kernel, dim3((total + 255) / 256), dim3(256), 0, stream,
                     p.W_ih, p.W_hh, p.Wopt);

  void* kargs[] = { (void*)&p };
  hipLaunchCooperativeKernel((const void*)mann_kernel, dim3(256), dim3(256), kargs, 0, stream);
}

// Round 3
// 28809.009 us; speedup vs baseline: 2.8114x; 1.2059x over previous
//
#include <hip/hip_runtime.h>

#define TT 512
#define BB 64
#define IDIM 256
#define CDIM 512
#define NMEM 128
#define MDIM 64
#define KTOT 832     // (IDIM + M) + CDIM = 320 + 512
#define ODIM 576     // CDIM + M
#define NROWS 2048   // 4*CDIM

struct Params {
  const float* embs; const float* W_ih; const float* W_hh; const float* b_ih; const float* b_hh;
  const float* W_kr; const float* b_kr; const float* w_br; const float* W_kw; const float* b_kw;
  const float* w_bw; const float* W_e; const float* b_e; const float* W_a; const float* b_a;
  const float* h0; const float* c0; const float* r0; const float* mem0;
  float* out;
  unsigned* flags; // [256]: A-flags (phase A done count), [256..320): B-flags
  float* Wopt;   // [2048*832] reordered as [w][k][lr]
  float* h_buf;  // [2][B*CDIM] double buffered
  float* r_buf;  // [B*M]
};

__device__ __forceinline__ float sigmoidf_(float x) { return 1.0f / (1.0f + __expf(-x)); }
__device__ __forceinline__ float tanhf_(float x) {
  float e = __expf(-2.0f * fabsf(x));
  float t = (1.0f - e) / (1.0f + e);
  return copysignf(t, x);
}
__device__ __forceinline__ float softplusf_(float x) {
  return (x > 20.0f) ? x : log1pf(__expf(x));
}
__device__ __forceinline__ float wred_sum(float v) {
#pragma unroll
  for (int off = 32; off > 0; off >>= 1) v += __shfl_xor(v, off, 64);
  return v;
}
__device__ __forceinline__ float wred_max(float v) {
#pragma unroll
  for (int off = 32; off > 0; off >>= 1) v = fmaxf(v, __shfl_xor(v, off, 64));
  return v;
}
__device__ __forceinline__ unsigned wred_minu(unsigned v) {
#pragma unroll
  for (int off = 32; off > 0; off >>= 1) {
    unsigned o = (unsigned)__shfl_xor((int)v, off, 64);
    v = (o < v) ? o : v;
  }
  return v;
}

__device__ __forceinline__ unsigned flag_ld(const unsigned* f) {
  return __hip_atomic_load(f, __ATOMIC_RELAXED, __HIP_MEMORY_SCOPE_AGENT);
}

// Publish: one wbl2 (release, no inv) + one relaxed agent store to a PRIVATE word.
// No shared-line RMW anywhere -> no cross-XCD atomic serialization.
__device__ __forceinline__ void flag_release(unsigned* f, unsigned val) {
  __builtin_amdgcn_fence(__ATOMIC_RELEASE, "agent");   // buffer_wbl2 only
  __hip_atomic_store(f, val, __ATOMIC_RELAXED, __HIP_MEMORY_SCOPE_AGENT);
}

// Wave-0-only wait: poll A-flags (and optionally B-flags) until all >= target,
// then one acquire fence (buffer_inv). Caller must __syncthreads() after.
__device__ __forceinline__ void grid_wait(const unsigned* flags, int lane,
                                          unsigned target, bool withB) {
  const unsigned* fA = flags + lane * 4;
  const unsigned* fB = flags + 256 + lane;
  for (;;) {
    unsigned a0 = flag_ld(fA + 0);
    unsigned a1 = flag_ld(fA + 1);
    unsigned a2 = flag_ld(fA + 2);
    unsigned a3 = flag_ld(fA + 3);
    unsigned m = a0 < a1 ? a0 : a1;
    unsigned n = a2 < a3 ? a2 : a3;
    m = m < n ? m : n;
    if (withB) { unsigned b = flag_ld(fB); m = b < m ? b : m; }
    m = wred_minu(m);
    if (m >= target) break;
    __builtin_amdgcn_s_sleep(1);
  }
  __builtin_amdgcn_fence(__ATOMIC_ACQUIRE, "agent");   // buffer_inv only
}

// Pre-transpose combined weights into Wopt[(w*832 + k)*8 + lr],
// lr -> global gate row = 512*(lr>>1) + 2*w + (lr&1)
__global__ void __launch_bounds__(256) transpose_w_kernel(const float* __restrict__ W_ih,
                                                          const float* __restrict__ W_hh,
                                                          float* __restrict__ Wopt) {
  int idx = blockIdx.x * 256 + threadIdx.x;
  if (idx >= NROWS * KTOT) return;
  int lr = idx & 7;
  int rem = idx >> 3;          // w*832 + k
  int k = rem % KTOT;
  int w = rem / KTOT;
  int row = 512 * (lr >> 1) + 2 * w + (lr & 1);
  float v = (k < 320) ? W_ih[(size_t)row * 320 + k] : W_hh[(size_t)row * 512 + (k - 320)];
  Wopt[idx] = v;
}

__global__ void __launch_bounds__(256) mann_kernel(Params p) {
  const int w = blockIdx.x;       // 0..255 : owns c-dims {2w, 2w+1}
  const int tid = threadIdx.x;
  const int lane = tid & 63;
  const int q = tid >> 6;         // wave id 0..3

  // phase-A staging (xs aliased with cross-wave reduce buffer)
  __shared__ __align__(16) float xs[64 * 65];          // [kk][b] stride 65 (conflict-free)
  __shared__ __align__(16) float ws[64][8];            // [kk][lr]
  __shared__ float bsum[8];
  // phase-B (batch WGs only)
  __shared__ __align__(16) float Mem_s[MDIM][NMEM + 1];  // [m][n] stride 129 (conflict-free)
  __shared__ __align__(16) float hb[CDIM];
  __shared__ float kw_s[MDIM], kr_s[MDIM], e_s[MDIM], a_s[MDIM];
  __shared__ float ww_s[NMEM], wr_s[NMEM];
  __shared__ float sc[8];  // 0:betaw 1:betar 2:|kw| 3:|kr| 4,5:max parts 6,7:sum parts

  // ---------------- init ----------------
  if (tid < 8) {
    int row = 512 * (tid >> 1) + 2 * w + (tid & 1);
    bsum[tid] = p.b_ih[row] + p.b_hh[row];
  }
  float c_reg = 0.0f;  // valid for tid<128: cell state for (b=tid&63, j=2w+(tid>>6))
  if (tid < 128) {
    int jj = tid >> 6, b = tid & 63;
    int j = 2 * w + jj;
    c_reg = p.c0[j];
    p.h_buf[(size_t)b * CDIM + j] = p.h0[j];  // h_buf[0]
  }
  if (w < BB) {
    for (int idx = tid; idx < NMEM * MDIM; idx += 256) {
      int n = idx >> 6, m = idx & 63;
      Mem_s[m][n] = p.mem0[idx];  // mem0[n][m] -> Mem_s[m][n]
    }
    if (tid < MDIM) p.r_buf[w * MDIM + tid] = p.r0[tid];
  }
  __syncthreads();
  if (tid == 0) {
    __builtin_amdgcn_fence(__ATOMIC_RELEASE, "agent");
    __hip_atomic_store(&p.flags[w], 1u, __ATOMIC_RELAXED, __HIP_MEMORY_SCOPE_AGENT);
    if (w < BB)
      __hip_atomic_store(&p.flags[256 + w], 1u, __ATOMIC_RELAXED, __HIP_MEMORY_SCOPE_AGENT);
  }

#pragma unroll 1
  for (int t = 0; t < TT; ++t) {
    // ---- step entry: h(t) buffer + r(t) ready, and prior readers of our
    //      h_write buffer are done (A >= t+1 and B >= t+1) ----
    if (tid < 64) grid_wait(p.flags, lane, (unsigned)(t + 1), true);
    __syncthreads();

    const float* h_read = p.h_buf + (size_t)(t & 1) * (BB * CDIM);
    float* h_write = p.h_buf + (size_t)((t + 1) & 1) * (BB * CDIM);

    // ---------------- Phase A: gates GEMM + LSTM ----------------
    float acc[8];
#pragma unroll
    for (int i = 0; i < 8; ++i) acc[i] = 0.0f;

    const int kk4 = (tid & 15) * 4;
    const int bb0 = tid >> 4;

    // prefetch chunk 0 (x-slice + weight-slice) into registers
    float4 vbuf[4];
    float wsv0, wsv1;
    {
      const int k = kk4;  // chunk 0 -> embs
#pragma unroll
      for (int i = 0; i < 4; ++i) {
        const int b = bb0 + 16 * i;
        vbuf[i] = *(const float4*)(p.embs + ((size_t)t * BB + b) * IDIM + k);
      }
      const float* src = p.Wopt + (size_t)w * KTOT * 8;
      wsv0 = src[tid];
      wsv1 = src[tid + 256];
    }

#pragma unroll 1
    for (int c = 0; c < 13; ++c) {
      // store prefetched x chunk + weight chunk to LDS
#pragma unroll
      for (int i = 0; i < 4; ++i) {
        const int b = bb0 + 16 * i;
        xs[(kk4 + 0) * 65 + b] = vbuf[i].x;
        xs[(kk4 + 1) * 65 + b] = vbuf[i].y;
        xs[(kk4 + 2) * 65 + b] = vbuf[i].z;
        xs[(kk4 + 3) * 65 + b] = vbuf[i].w;
      }
      ((float*)ws)[tid] = wsv0;
      ((float*)ws)[tid + 256] = wsv1;
      __syncthreads();

      // issue next chunk's global loads (overlap with compute below)
      if (c < 12) {
        const int cn = c + 1;
        const int k = cn * 64 + kk4;
#pragma unroll
        for (int i = 0; i < 4; ++i) {
          const int b = bb0 + 16 * i;
          if (cn < 4)       vbuf[i] = *(const float4*)(p.embs + ((size_t)t * BB + b) * IDIM + k);
          else if (cn == 4) vbuf[i] = *(const float4*)(p.r_buf + b * MDIM + (k - 256));
          else              vbuf[i] = *(const float4*)(h_read + (size_t)b * CDIM + (k - 320));
        }
        const float* src = p.Wopt + ((size_t)w * KTOT + cn * 64) * 8;
        wsv0 = src[tid];
        wsv1 = src[tid + 256];
      }

      // wave q computes kk in [16q, 16q+16) for all 8 rows (K-split across waves)
      const int kkb = 16 * q;
#pragma unroll
      for (int kki = 0; kki < 16; ++kki) {
        const int kk = kkb + kki;
        const float xv = xs[kk * 65 + lane];
        const float4 w0 = *(const float4*)&ws[kk][0];
        const float4 w1 = *(const float4*)&ws[kk][4];
        acc[0] = fmaf(xv, w0.x, acc[0]);
        acc[1] = fmaf(xv, w0.y, acc[1]);
        acc[2] = fmaf(xv, w0.z, acc[2]);
        acc[3] = fmaf(xv, w0.w, acc[3]);
        acc[4] = fmaf(xv, w1.x, acc[4]);
        acc[5] = fmaf(xv, w1.y, acc[5]);
        acc[6] = fmaf(xv, w1.z, acc[6]);
        acc[7] = fmaf(xv, w1.w, acc[7]);
      }
      __syncthreads();
    }
    // cross-wave K reduction (reuse xs region)
    {
      float* red = xs;  // [q][lr][b] = [4][8][64]
#pragma unroll
      for (int lr = 0; lr < 8; ++lr) red[(q * 8 + lr) * 64 + lane] = acc[lr];
      __syncthreads();
      if (tid < 128) {
        const int jj = tid >> 6, b = tid & 63;
        float g[4];
#pragma unroll
        for (int gate = 0; gate < 4; ++gate) {
          const int lr = gate * 2 + jj;
          float s = bsum[lr];
#pragma unroll
          for (int qq = 0; qq < 4; ++qq) s += red[(qq * 8 + lr) * 64 + b];
          g[gate] = s;
        }
        const float iv = sigmoidf_(g[0]);
        const float fv = sigmoidf_(g[1]);
        const float gv = tanhf_(g[2]);
        const float ov = sigmoidf_(g[3]);
        c_reg = fv * c_reg + iv * gv;
        const float hv = ov * tanhf_(c_reg);
        h_write[(size_t)b * CDIM + 2 * w + jj] = hv;
      }
    }
    // ---- publish phase A (private flag, no contention) ----
    __syncthreads();
    if (tid == 0) flag_release(&p.flags[w], (unsigned)(t + 2));

    // ---------------- Phase B: heads + addressing + memory (batch WGs) ----------------
    if (w < BB) {
      // wait for ALL producers' h(t) slices
      if (tid < 64) grid_wait(p.flags, lane, (unsigned)(t + 2), false);
      __syncthreads();

      const int b = w;
      hb[tid] = h_write[(size_t)b * CDIM + tid];
      hb[tid + 256] = h_write[(size_t)b * CDIM + tid + 256];
      __syncthreads();
      // head GEMVs: [0,64):kw  [64,128):e  [128,192):kr  192:betaw 193:betar
      if (tid < 194) {
        const float* Wrow;
        if (tid < 64)        Wrow = p.W_kw + (size_t)tid * CDIM;
        else if (tid < 128)  Wrow = p.W_e + (size_t)(tid - 64) * CDIM;
        else if (tid < 192)  Wrow = p.W_kr + (size_t)(tid - 128) * CDIM;
        else if (tid == 192) Wrow = p.w_bw;
        else                 Wrow = p.w_br;
        float s = 0.0f;
#pragma unroll 4
        for (int k = 0; k < CDIM; k += 4) {
          const float4 wv = *(const float4*)(Wrow + k);
          s = fmaf(wv.x, hb[k], s);
          s = fmaf(wv.y, hb[k + 1], s);
          s = fmaf(wv.z, hb[k + 2], s);
          s = fmaf(wv.w, hb[k + 3], s);
        }
        if (tid < 64)       kw_s[tid] = tanhf_(s + p.b_kw[tid]);
        else if (tid < 128) e_s[tid - 64] = sigmoidf_(s + p.b_e[tid - 64]);
        else if (tid < 192) kr_s[tid - 128] = tanhf_(s + p.b_kr[tid - 128]);
        else                sc[tid - 192] = softplusf_(s);
      }
      // a = tanh(emb @ W_a^T + b_a)
      if (tid < 64) {
        const float* Wrow = p.W_a + (size_t)tid * IDIM;
        const float* eb = p.embs + ((size_t)t * BB + b) * IDIM;
        float s = p.b_a[tid];
#pragma unroll 4
        for (int k = 0; k < IDIM; k += 4) {
          const float4 wv = *(const float4*)(Wrow + k);
          const float4 ev = *(const float4*)(eb + k);
          s = fmaf(wv.x, ev.x, s);
          s = fmaf(wv.y, ev.y, s);
          s = fmaf(wv.z, ev.z, s);
          s = fmaf(wv.w, ev.w, s);
        }
        a_s[tid] = tanhf_(s);
      }
      __syncthreads();
      // key norms: wave0 -> |kw|, wave1 -> |kr|
      if (tid < 128) {
        const float v = (q == 0) ? kw_s[lane] : kr_s[lane];
        const float ss = wred_sum(v * v);
        if (lane == 0) sc[2 + q] = sqrtf(ss);
      }
      __syncthreads();
      // ---- write addressing (on old Mem) ----
      {
        float logit = 0.0f, ex = 0.0f;
        const float beta = sc[0], keyn = sc[2];
        if (tid < 128) {
          float sim = 0.0f, nrm = 0.0f;
#pragma unroll 8
          for (int m = 0; m < MDIM; ++m) {
            const float mv = Mem_s[m][tid];
            sim = fmaf(mv, kw_s[m], sim);
            nrm = fmaf(mv, mv, nrm);
          }
          logit = beta * sim / (sqrtf(nrm) * keyn + 1e-8f);
          const float mx = wred_max(logit);
          if (lane == 0) sc[4 + q] = mx;
        }
        __syncthreads();
        if (tid < 128) {
          ex = __expf(logit - fmaxf(sc[4], sc[5]));
          const float sm = wred_sum(ex);
          if (lane == 0) sc[6 + q] = sm;
        }
        __syncthreads();
        if (tid < 128) ww_s[tid] = ex / (sc[6] + sc[7]);
        __syncthreads();
      }
      // ---- memory write (erase/add) ----
      for (int idx = tid; idx < NMEM * MDIM; idx += 256) {
        const int m = idx >> 7, n = idx & 127;
        const float mv = Mem_s[m][n];
        Mem_s[m][n] = mv * (1.0f - ww_s[n] * e_s[m]) + ww_s[n] * a_s[m];
      }
      __syncthreads();
      // ---- read addressing (on new Mem) ----
      {
        float logit = 0.0f, ex = 0.0f;
        const float beta = sc[1], keyn = sc[3];
        if (tid < 128) {
          float sim = 0.0f, nrm = 0.0f;
#pragma unroll 8
          for (int m = 0; m < MDIM; ++m) {
            const float mv = Mem_s[m][tid];
            sim = fmaf(mv, kr_s[m], sim);
            nrm = fmaf(mv, mv, nrm);
          }
          logit = beta * sim / (sqrtf(nrm) * keyn + 1e-8f);
          const float mx = wred_max(logit);
          if (lane == 0) sc[4 + q] = mx;
        }
        __syncthreads();
        if (tid < 128) {
          ex = __expf(logit - fmaxf(sc[4], sc[5]));
          const float sm = wred_sum(ex);
          if (lane == 0) sc[6 + q] = sm;
        }
        __syncthreads();
        if (tid < 128) wr_s[tid] = ex / (sc[6] + sc[7]);
        __syncthreads();
      }
      // ---- read vector + outputs ----
      if (tid < 64) {
        float rv = 0.0f;
#pragma unroll 8
        for (int n = 0; n < NMEM; ++n) rv = fmaf(wr_s[n], Mem_s[tid][n], rv);
        p.r_buf[b * MDIM + tid] = rv;
        p.out[((size_t)t * BB + b) * ODIM + 512 + tid] = rv;
      }
      p.out[((size_t)t * BB + b) * ODIM + tid] = hb[tid];
      p.out[((size_t)t * BB + b) * ODIM + 256 + tid] = hb[tid + 256];
      // ---- publish phase B (private flag) ----
      __syncthreads();
      if (tid == 0) flag_release(&p.flags[256 + w], (unsigned)(t + 2));
    }
  }
}

extern "C" void kernel_launch(void* const* d_in, const int* in_sizes, int n_in,
                              void* d_out, int out_size, void* d_ws, size_t ws_size,
                              hipStream_t stream) {
  (void)in_sizes; (void)n_in; (void)out_size; (void)ws_size;
  Params p;
  p.embs = (const float*)d_in[0];
  p.W_ih = (const float*)d_in[1];
  p.W_hh = (const float*)d_in[2];
  p.b_ih = (const float*)d_in[3];
  p.b_hh = (const float*)d_in[4];
  p.W_kr = (const float*)d_in[5];
  p.b_kr = (const float*)d_in[6];
  p.w_br = (const float*)d_in[7];
  p.W_kw = (const float*)d_in[8];
  p.b_kw = (const float*)d_in[9];
  p.w_bw = (const float*)d_in[10];
  p.W_e  = (const float*)d_in[11];
  p.b_e  = (const float*)d_in[12];
  p.W_a  = (const float*)d_in[13];
  p.b_a  = (const float*)d_in[14];
  p.h0   = (const float*)d_in[15];
  p.c0   = (const float*)d_in[16];
  p.r0   = (const float*)d_in[17];
  p.mem0 = (const float*)d_in[18];
  p.out = (float*)d_out;

  float* ws = (float*)d_ws;
  p.flags = (unsigned*)ws;                  // 320 uints used, 512 reserved
  p.Wopt = ws + 512;                        // 2048*832      = 1,703,936 floats
  p.h_buf = p.Wopt + (size_t)NROWS * KTOT;  // 2*64*512      = 65,536 floats
  p.r_buf = p.h_buf + 2 * BB * CDIM;        // 64*64         = 4,096 floats

  hipMemsetAsync(p.flags, 0, 512 * sizeof(unsigned), stream);

  const int total = NROWS * KTOT;
  hipLaunchKernelGGL(transpose_w_kernel, dim3((total + 255) / 256), dim3(256), 0, stream,
                     p.W_ih, p.W_hh, p.Wopt);

  void* kargs[] = { (void*)&p };
  hipLaunchCooperativeKernel((const void*)mann_kernel, dim3(256), dim3(256), kargs, 0, stream);
}